// Round 19
// baseline (267.543 us; speedup 1.0000x reference)
//
#include <hip/hip_runtime.h>
#include <hip/hip_bf16.h>

#define T_ 4
#define C_ 64
#define H_ 128
#define W_ 128
#define CI_ 16
#define PS_ 7
#define NC_ 729       // 27*27 candidates per query
#define NCP_ 732      // distG row stride: 732 = 4*183 -> every row 16B-aligned
#define S0_ 4
#define KS_ 100
#define NQ_ 1024      // 32*32 queries per frame
#define SCALE_ 10.0f
#define HW_ (H_*W_)
#define RW_ 45        // region dim (float4); 45%8=5 -> bank rotation
#define WR_ 37        // dist half-window rows (13 apron + 8 + 16 reach)
#define WN_ (WR_*RW_) // 1665 float4 per half-window (26.6 KB)
#define LCAP_ 768
#define CB_ 8         // conv channel batch (24 dwordx4 in flight)
#define CH_ 32        // conv input-channel half (2x grid -> 4 waves/SIMD)

typedef float v2f __attribute__((ext_vector_type(2)));
#if __has_builtin(__builtin_elementwise_fma)
#define VFMA(a, b, c) __builtin_elementwise_fma((a), (b), (c))
#else
#define VFMA(a, b, c) ((a) * (b) + (c))
#endif

__device__ __forceinline__ float4 f4add(float4 a, float4 b) {
  return make_float4(a.x + b.x, a.y + b.y, a.z + b.z, a.w + b.w);
}

// ------- FUSED conv 3x3 + conv 1x1, INPUT-CHANNEL-SPLIT (R14-verified) ------
__device__ __forceinline__ float4 colfix(float4 r, bool loB, bool hiB) {
  float4 o;
  o.x = loB ? 0.f : (hiB ? r.y : r.x);
  o.y = loB ? r.x : (hiB ? r.z : r.y);
  o.z = loB ? r.y : (hiB ? r.w : r.z);
  o.w = loB ? r.z : (hiB ? 0.f : r.w);
  return o;
}

__global__ __launch_bounds__(128, 1) void conv_fused_kernel(
    const float* __restrict__ vid, const float* __restrict__ gw,
    const float* __restrict__ gb, const float* __restrict__ tw,
    const float* __restrict__ tb, float4* __restrict__ v1A,
    float4* __restrict__ v1B, float4* __restrict__ v2A,
    float4* __restrict__ v2B) {
  __shared__ float wls[CH_ * 9 * 4];   // 3x3 weights [c_loc][k][co]
  __shared__ float tls[CH_ * 4];       // 1x1 weights [c_loc][co]
  const int tid = threadIdx.x;
  const int g = blockIdx.y;
  const int t = blockIdx.z & 3, half = blockIdx.z >> 2;
  for (int m = tid; m < CH_ * 9 * 4; m += 128) {
    int co = m & 3, ck = m >> 2;       // ck = c_loc*9 + k in [0,288)
    wls[m] = gw[((size_t)(g * 4 + co) * C_) * 9 + half * (CH_ * 9) + ck];
  }
  for (int m = tid; m < CH_ * 4; m += 128) {
    int o = m & 3, c = m >> 2;
    tls[m] = tw[(g * 4 + o) * C_ + half * CH_ + c];
  }
  __syncthreads();
  const int ti0 = (blockIdx.x >> 3) * 16, tj0 = (blockIdx.x & 7) * 16;
  const int u = tid >> 3, v = tid & 7;   // 16 rows x 8 col-pairs
  const int i = ti0 + u, j0 = tj0 + 2 * v;
  const int c0 = j0 - 1;
  const int c0c = min(max(c0, 0), W_ - 4);
  const bool loB = (c0 < 0), hiB = (c0 > W_ - 4);
  const int rm1 = max(i - 1, 0), rp1 = min(i + 1, H_ - 1);
  const float mk0 = (i > 0) ? 1.f : 0.f;
  const float mk2 = (i < H_ - 1) ? 1.f : 0.f;
  const int o0 = rm1 * W_ + c0c, o1 = i * W_ + c0c, o2 = rp1 * W_ + c0c;

  float accA[4], accB[4], acc1A[4], acc1B[4];
#pragma unroll
  for (int co = 0; co < 4; ++co) {     // bias carried by half 0 only
    float bg = half ? 0.f : gb[g * 4 + co];
    float bt = half ? 0.f : tb[g * 4 + co];
    accA[co] = bg; accB[co] = bg;
    acc1A[co] = bt; acc1B[co] = bt;
  }

  const float* vb = vid + ((size_t)t * C_ + half * CH_) * HW_;
#pragma unroll 1
  for (int cb = 0; cb < CH_; cb += CB_) {
    float4 r[CB_][3];
#pragma unroll
    for (int c = 0; c < CB_; ++c) {       // 24 UNCONDITIONAL loads -> in flight
      const float* p = vb + (size_t)(cb + c) * HW_;
      r[c][0] = *(const float4*)(p + o0);
      r[c][1] = *(const float4*)(p + o1);
      r[c][2] = *(const float4*)(p + o2);
    }
#pragma unroll
    for (int c = 0; c < CB_; ++c) {
      float4 f0 = colfix(r[c][0], loB, hiB);
      float4 f1 = colfix(r[c][1], loB, hiB);
      float4 f2 = colfix(r[c][2], loB, hiB);
      f0.x *= mk0; f0.y *= mk0; f0.z *= mk0; f0.w *= mk0;
      f2.x *= mk2; f2.y *= mk2; f2.z *= mk2; f2.w *= mk2;
      const float* wc = &wls[(cb + c) * 36];
      const float* tc = &tls[(cb + c) * 4];
      float e0[4] = {f0.x, f0.y, f0.z, f0.w};
      float e1[4] = {f1.x, f1.y, f1.z, f1.w};
      float e2[4] = {f2.x, f2.y, f2.z, f2.w};
#pragma unroll
      for (int co = 0; co < 4; ++co) {     // fused 1x1: center pixels j0, j0+1
        acc1A[co] = fmaf(tc[co], e1[1], acc1A[co]);
        acc1B[co] = fmaf(tc[co], e1[2], acc1B[co]);
      }
#pragma unroll
      for (int kj = 0; kj < 3; ++kj) {
#pragma unroll
        for (int co = 0; co < 4; ++co) {
          accA[co] = fmaf(wc[(0 * 3 + kj) * 4 + co], e0[kj],     accA[co]);
          accB[co] = fmaf(wc[(0 * 3 + kj) * 4 + co], e0[kj + 1], accB[co]);
          accA[co] = fmaf(wc[(1 * 3 + kj) * 4 + co], e1[kj],     accA[co]);
          accB[co] = fmaf(wc[(1 * 3 + kj) * 4 + co], e1[kj + 1], accB[co]);
          accA[co] = fmaf(wc[(2 * 3 + kj) * 4 + co], e2[kj],     accA[co]);
          accB[co] = fmaf(wc[(2 * 3 + kj) * 4 + co], e2[kj + 1], accB[co]);
        }
      }
    }
  }
  float4* v1o = half ? v1B : v1A;
  float4* v2o = half ? v2B : v2A;
  const size_t o = ((size_t)g * T_ + t) * HW_ + i * W_ + j0;
  v1o[o]     = make_float4(accA[0], accA[1], accA[2], accA[3]);
  v1o[o + 1] = make_float4(accB[0], accB[1], accB[2], accB[3]);
  v2o[o]     = make_float4(acc1A[0], acc1A[1], acc1A[2], acc1A[3]);
  v2o[o + 1] = make_float4(acc1B[0], acc1B[1], acc1B[2], acc1B[3]);
}

// ---------------- dists: QUARTER-BLOCKS (256 thr = 4 waves = 1 pair-row) ----
// Block-size matrix from R5/R14/R15/R17: 128-thr blocks co-schedule multiple
// per CU (conv split worked); 512/1024-thr don't (occ stuck ~19%/~50%).
// Untested cell: 256 thr. Split each 16x16 region into two 8-row halves:
// grid (128,T), block = 1 pair-row x 4 col-tiles (per-wave geometry, LDS
// reads, FMAs all unchanged; total waves/frame 512 unchanged). Private
// 37x45 window = 26.6KB single buffer -> 4 blocks/CU = 106KB LDS, 16
// waves/CU target. No reg prefetch: cross-block TLP is the latency hider
// under test. launch_bounds(256,4) -> 128-VGPR cap (need ~100).
// Falsifier: occ stays ~19% or spill -> revert to R18 mono.
__global__ __launch_bounds__(256, 4) void dist_kernel(
    const float4* __restrict__ v1A, const float4* __restrict__ v1B,
    float* __restrict__ out) {
  __shared__ float4 Rs[WN_];                     // 26.6 KiB
  const int tid = threadIdx.x;
  const int t = blockIdx.y;
  const int region = blockIdx.x >> 1, h = blockIdx.x & 1;
  const int qi0 = (region >> 3) * 16, qj0 = (region & 7) * 16;
  const int w = tid >> 6, lane = tid & 63;
  const int dj = w * 4;                          // col-tile 0..3
  const int qi_p = qi0 + 8 * h;                  // q0 pixel row; q1 = qi_p+4
  const int qj = qj0 + dj;
  const int la = lane >> 1, bg = lane & 1;
  const int b_lo = max(13 - qj, 0);
  const int bs = bg ? 13 : b_lo;
  const int a_lo0 = max(13 - qi_p, 0);
  const int a_lo1 = max(9 - qi_p, 0);
  const bool compute_ok = (la < 31);

  // staging: 7 float4 per thread per chunk; clamped source, linear dest
  // (tail threads clamp to WN_-1: duplicate same-value writes, benign)
  int soff[7];
#pragma unroll
  for (int k = 0; k < 7; ++k) {
    int p = min(tid + 256 * k, WN_ - 1);
    int uu = p / RW_, vv = p - uu * RW_;
    int row = min(max(qi_p - 13 + uu, 0), H_ - 1);
    int col = min(max(qj0 - 13 + vv, 0), W_ - 1);
    soff[k] = row * W_ + col;
  }

  v2f acc0[14], acc1[14];
#pragma unroll
  for (int j = 0; j < 14; ++j) { acc0[j] = (v2f){0.f, 0.f}; acc1[j] = (v2f){0.f, 0.f}; }

#pragma unroll 1
  for (int ci = 0; ci < 4; ++ci) {
    const float4* sA = v1A + ((size_t)ci * T_ + t) * HW_;
    const float4* sB = v1B + ((size_t)ci * T_ + t) * HW_;
#pragma unroll
    for (int k = 0; k < 7; ++k) {
      int p = min(tid + 256 * k, WN_ - 1);
      Rs[p] = f4add(sA[soff[k]], sB[soff[k]]);
    }
    __syncthreads();                              // window ready
    if (compute_ok) {
#pragma unroll 1
      for (int r = 0; r < 7; ++r) {
        v2f q0lo[7], q0hi[7], q1lo[7], q1hi[7];
        const float4* q0row = &Rs[(13 + r) * RW_ + dj + 13];
#pragma unroll
        for (int s = 0; s < 7; ++s) {
          float4 qq = q0row[s];                 // q0 patch row (broadcast)
          q0lo[s] = (v2f){qq.x, qq.y};
          q0hi[s] = (v2f){qq.z, qq.w};
          float4 q2 = q0row[4 * RW_ + s];       // q1 patch row = +4 rows
          q1lo[s] = (v2f){q2.x, q2.y};
          q1hi[s] = (v2f){q2.z, q2.w};
        }
        const float4* crow = &Rs[(la + r) * RW_ + dj + bs];
#pragma unroll
        for (int y = 0; y < 20; ++y) {
          float4 vv4 = crow[y];                 // shared by q0 AND q1
          v2f vlo = (v2f){vv4.x, vv4.y}, vhi = (v2f){vv4.z, vv4.w};
          const int s_lo = (y > 13) ? (y - 13) : 0;
          const int s_hi = (y < 6) ? y : 6;
#pragma unroll
          for (int s = s_lo; s <= s_hi; ++s) {
            int j = y - s;
            acc0[j] = VFMA(q0lo[s], vlo, acc0[j]);
            acc0[j] = VFMA(q0hi[s], vhi, acc0[j]);
            acc1[j] = VFMA(q1lo[s], vlo, acc1[j]);
            acc1[j] = VFMA(q1hi[s], vhi, acc1[j]);
          }
        }
      }
    }
    __syncthreads();                              // reads done before re-stage
  }
  if (compute_ok) {
    const int q0q = ((qi_p >> 2) << 5) + (qj >> 2);
    if (la >= a_lo0 && la <= 26) {
      float* o = out + ((size_t)t * NQ_ + q0q) * NCP_ + la * 27 + bs;
#pragma unroll
      for (int j = 0; j < 14; ++j) o[j] = acc0[j].x + acc0[j].y;
    }
    const int a1 = la - 4;
    if (a1 >= a_lo1 && a1 <= 26) {
      float* o = out + ((size_t)t * NQ_ + (q0q + 32)) * NCP_ + a1 * 27 + bs;
#pragma unroll
      for (int j = 0; j < 14; ++j) o[j] = acc1[j].x + acc1[j].y;
    }
  }
}

// ---------------- select: 2-level radix top-100, wave-primitive scans -------
// Interior fast path (77% of queries): clamp remap is identity and the
// 729-row is contiguous + 16B-aligned -> vectorized float4 loads.
__global__ __launch_bounds__(256) void select_kernel(
    const float* __restrict__ distA, int* __restrict__ sel_n,
    float* __restrict__ sel_w, float* __restrict__ wsum_out) {
  __shared__ float dist[NC_];
  __shared__ unsigned int ukey[NC_];
  __shared__ float redf[4];
  __shared__ unsigned int hist[256];
  __shared__ int lk[LCAP_];
  __shared__ unsigned int lkey[LCAP_];
  __shared__ unsigned int scal[6];   // 0=beta 1=run 2=cursor 3=listlen 4=beta2 5=run2

  const int tid = threadIdx.x;
  const int lane = tid & 63, wid = tid >> 6;
  const int q = blockIdx.x, t = blockIdx.y;
  const int qi = (q >> 5) * S0_, qj = (q & 31) * S0_;
  const int a_lo = max(13 - qi, 0), b_lo = max(13 - qj, 0);
  const size_t base = ((size_t)t * NQ_ + q) * NCP_;

  for (int h = tid; h < 256; h += 256) hist[h] = 0;
  if (tid == 0) { scal[2] = 0; scal[3] = 0; }
  float lmax = -INFINITY;
  if (a_lo == 0 && b_lo == 0) {            // interior: vectorized direct load
    if (tid < 182) {
      float4 d4 = *(const float4*)(distA + base + 4 * tid);
      float dv[4] = {d4.x, d4.y, d4.z, d4.w};
#pragma unroll
      for (int e = 0; e < 4; ++e) {
        int k = 4 * tid + e;
        float d = dv[e];
        dist[k] = d;
        unsigned int u = __float_as_uint(d);
        ukey[k] = u ^ (((unsigned int)((int)u >> 31)) | 0x80000000u);
        lmax = fmaxf(lmax, d);
      }
    } else if (tid == 182) {
      float d = distA[base + 728];
      dist[728] = d;
      unsigned int u = __float_as_uint(d);
      ukey[728] = u ^ (((unsigned int)((int)u >> 31)) | 0x80000000u);
      lmax = d;
    }
  } else {                                 // boundary: scalar clamp-gather
    for (int k = tid; k < NC_; k += 256) {
      int aa = k / 27, bb = k - aa * 27;
      int kk = max(aa, a_lo) * 27 + max(bb, b_lo);
      float d = distA[base + kk];
      dist[k] = d;
      unsigned int u = __float_as_uint(d);
      ukey[k] = u ^ (((unsigned int)((int)u >> 31)) | 0x80000000u);
      lmax = fmaxf(lmax, d);
    }
  }
#pragma unroll
  for (int off = 32; off > 0; off >>= 1)
    lmax = fmaxf(lmax, __shfl_down(lmax, off, 64));
  if (lane == 0) redf[wid] = lmax;
  __syncthreads();                                             // B1
  const float dmax = fmaxf(fmaxf(redf[0], redf[1]), fmaxf(redf[2], redf[3]));
  for (int k = tid; k < NC_; k += 256) atomicAdd(&hist[ukey[k] >> 24], 1u);
  __syncthreads();                                             // B2
  if (wid == 0) {
    int s4 = (int)(hist[lane * 4] + hist[lane * 4 + 1] + hist[lane * 4 + 2] + hist[lane * 4 + 3]);
    int s = s4;
#pragma unroll
    for (int off = 1; off < 64; off <<= 1) {
      int o = __shfl_down(s, off, 64);
      if (lane + off < 64) s += o;
    }
    int above = s - s4;
    if (above < KS_ && s >= KS_) {
      int run = above;
#pragma unroll
      for (int bb = 3; bb >= 0; --bb) {
        int h = (int)hist[lane * 4 + bb];
        if (run + h >= KS_) { scal[0] = (unsigned int)(lane * 4 + bb); scal[1] = (unsigned int)run; break; }
        run += h;
      }
    }
  }
  __syncthreads();                                             // B3
  const unsigned int beta = scal[0];
  const int run = (int)scal[1];
  for (int h = tid; h < 256; h += 256) hist[h] = 0;
  __syncthreads();                                             // B4
  for (int k = tid; k < NC_; k += 256)
    if ((ukey[k] >> 24) == beta) atomicAdd(&hist[(ukey[k] >> 16) & 0xFFu], 1u);
  __syncthreads();                                             // B5
  if (wid == 0) {
    int s4 = (int)(hist[lane * 4] + hist[lane * 4 + 1] + hist[lane * 4 + 2] + hist[lane * 4 + 3]);
    int s = s4;
#pragma unroll
    for (int off = 1; off < 64; off <<= 1) {
      int o = __shfl_down(s, off, 64);
      if (lane + off < 64) s += o;
    }
    int above = run + s - s4;
    if (above < KS_ && run + s >= KS_) {
      int r2 = above;
#pragma unroll
      for (int bb = 3; bb >= 0; --bb) {
        int h = (int)hist[lane * 4 + bb];
        if (r2 + h >= KS_) { scal[4] = (unsigned int)(lane * 4 + bb); scal[5] = (unsigned int)r2; break; }
        r2 += h;
      }
    }
  }
  __syncthreads();                                             // B6
  const unsigned int beta2 = scal[4];
  const int run2 = (int)scal[5];
  const size_t outb = ((size_t)t * NQ_ + q) * KS_;
  float lsum = 0.f;
  for (int k = tid; k < NC_; k += 256) {
    unsigned int key = ukey[k];
    unsigned int bin = key >> 24;
    bool sel = false, bdry = false;
    if (bin > beta) sel = true;
    else if (bin == beta) {
      unsigned int b2 = (key >> 16) & 0xFFu;
      if (b2 > beta2) sel = true;
      else if (b2 == beta2) bdry = true;
    }
    if (sel) {
      unsigned int slot = atomicAdd(&scal[2], 1u);
      int aa = k / 27, bb = k - aa * 27;
      int ni = min(max(qi + aa - 13, 0), H_ - 1);
      int nj = min(max(qj + bb - 13, 0), W_ - 1);
      float wv = __expf(SCALE_ * (dist[k] - dmax));
      sel_n[outb + slot] = (ni << 7) | nj;
      sel_w[outb + slot] = wv;
      lsum += wv;
    } else if (bdry) {
      unsigned int pos = atomicAdd(&scal[3], 1u);
      if (pos < LCAP_) { lk[pos] = k; lkey[pos] = key; }
    }
  }
  __syncthreads();                                             // B7
  const int L = min((int)scal[3], LCAP_);
  for (int i = tid; i < L; i += 256) {
    unsigned int key = lkey[i];
    int k = lk[i];
    int cnt = run2;
    for (int m = 0; m < L; ++m)
      cnt += (int)((lkey[m] > key) || (lkey[m] == key && lk[m] < k));
    if (cnt < KS_) {
      unsigned int slot = atomicAdd(&scal[2], 1u);
      int aa = k / 27, bb = k - aa * 27;
      int ni = min(max(qi + aa - 13, 0), H_ - 1);
      int nj = min(max(qj + bb - 13, 0), W_ - 1);
      float wv = __expf(SCALE_ * (dist[k] - dmax));
      sel_n[outb + slot] = (ni << 7) | nj;
      sel_w[outb + slot] = wv;
      lsum += wv;
    }
  }
#pragma unroll
  for (int off = 32; off > 0; off >>= 1) lsum += __shfl_down(lsum, off, 64);
  __syncthreads();                                             // B8
  if (lane == 0) redf[wid] = lsum;
  __syncthreads();                                             // B9
  if (tid == 0) wsum_out[t * NQ_ + q] = (redf[0] + redf[1]) + (redf[2] + redf[3]);
}

// ---------------- fold-count helper (analytic normalization) ----------------
__device__ __forceinline__ int cov_axis(int x) {
  int c = 0;
#pragma unroll
  for (int r = 0; r < 7; ++r) {
    if (x < H_ - 1) {
      int qb = x - r;
      c += (qb >= 0 && (qb & 3) == 0) ? 1 : 0;
    } else {
      c += (r >= 3) ? 1 : 0;
    }
  }
  return c;
}

// ------- weighted aggregation + fold + fused norm, Z-SPLIT (R15-verified) ---
// R16: LDS-pipe-saturated (6400 b128 gathers + conflicts ~ 43us/CU) -> at
// structural floor.
__global__ __launch_bounds__(1024) void agg_kernel(
    const float4* __restrict__ v2A, const float4* __restrict__ v2B,
    const int* __restrict__ sel_n, const float* __restrict__ sel_w,
    const float* __restrict__ wsum, float* __restrict__ Y) {
  __shared__ float4 Rs[RW_ * RW_];
  __shared__ int s_off[16][KS_];
  __shared__ float s_w[16][KS_];
  const int tid = threadIdx.x;
  const int t = blockIdx.y;
  const int cc0 = blockIdx.z * 2;
  const int qi0 = (blockIdx.x >> 3) * 16, qj0 = (blockIdx.x & 7) * 16;
  const int w = tid >> 6, lane = tid & 63;
  const int di = (w >> 2) * 4, dj = (w & 3) * 4;
  const int qi = qi0 + di, qj = qj0 + dj;
  const int q = ((qi >> 2) << 5) + (qj >> 2);
  const size_t base = ((size_t)t * NQ_ + q) * KS_;
  const float inv = 1.0f / wsum[t * NQ_ + q];
  for (int k = lane; k < KS_; k += 64) {
    int n = sel_n[base + k];
    int ni = n >> 7, nj = n & 127;
    s_off[w][k] = (ni - qi0 + 13) * RW_ + (nj - qj0 + 13);
    s_w[w][k] = sel_w[base + k] * inv;
  }
  const int r = lane / 7, s = lane - r * 7;    // valid for lane < 49
  const int myo = r * RW_ + s;
  const int oi = min(qi + r, H_ - 1), oj = min(qj + s, W_ - 1);
  const float invZ = 1.0f / (float)(cov_axis(oi) * cov_axis(oj));
#pragma unroll 1
  for (int ci = 0; ci < 2; ++ci) {
    const int cc = cc0 + ci;
    __syncthreads();
    const float4* sA = v2A + ((size_t)cc * T_ + t) * HW_;
    const float4* sB = v2B + ((size_t)cc * T_ + t) * HW_;
    for (int p = tid; p < RW_ * RW_; p += 1024) {
      int uu = p / RW_, vv = p - uu * RW_;
      int row = min(max(qi0 - 13 + uu, 0), H_ - 1);
      int col = min(max(qj0 - 13 + vv, 0), W_ - 1);
      const int so = row * W_ + col;
      Rs[p] = f4add(sA[so], sB[so]);
    }
    __syncthreads();
    if (lane < 49) {
      float4 acc = make_float4(0.f, 0.f, 0.f, 0.f);
#pragma unroll 4
      for (int k = 0; k < KS_; ++k) {
        float wv = s_w[w][k];
        float4 v = Rs[s_off[w][k] + myo];
        acc.x = fmaf(wv, v.x, acc.x);
        acc.y = fmaf(wv, v.y, acc.y);
        acc.z = fmaf(wv, v.z, acc.z);
        acc.w = fmaf(wv, v.w, acc.w);
      }
      float* yb = Y + (((size_t)t * CI_ + cc * 4) * H_ + oi) * W_ + oj;
      atomicAdd(yb, acc.x * invZ);
      atomicAdd(yb + HW_, acc.y * invZ);
      atomicAdd(yb + 2 * HW_, acc.z * invZ);
      atomicAdd(yb + 3 * HW_, acc.w * invZ);
    }
  }
}

extern "C" void kernel_launch(void* const* d_in, const int* in_sizes, int n_in,
                              void* d_out, int out_size, void* d_ws, size_t ws_size,
                              hipStream_t stream) {
  const float* vid     = (const float*)d_in[0];
  const float* g_w     = (const float*)d_in[1];
  const float* g_b     = (const float*)d_in[2];
  const float* theta_w = (const float*)d_in[3];
  const float* theta_b = (const float*)d_in[4];
  float* Y = (float*)d_out;

  // workspace: v1A | v1B | v2A | v2B | distG(NCP_) | sel_n | sel_w | wsum
  const size_t VSZ = (size_t)4 * T_ * HW_ * 4;                 // 1048576 floats
  float* v1A   = (float*)d_ws;
  float* v1B   = v1A + VSZ;
  float* v2A   = v1B + VSZ;
  float* v2B   = v2A + VSZ;
  float* distG = v2B + VSZ;
  int*   sel_n = (int*)(distG + (size_t)T_ * NQ_ * NCP_);      // 2998272
  float* sel_w = (float*)(sel_n + (size_t)T_ * NQ_ * KS_);     // 409600
  float* wsumv = sel_w + (size_t)T_ * NQ_ * KS_;               // 409600

  hipMemsetAsync(Y, 0, (size_t)out_size * sizeof(float), stream);

  conv_fused_kernel<<<dim3(64, 4, 2 * T_), 128, 0, stream>>>(
      vid, g_w, g_b, theta_w, theta_b,
      (float4*)v1A, (float4*)v1B, (float4*)v2A, (float4*)v2B);
  dist_kernel<<<dim3(128, T_), 256, 0, stream>>>(
      (const float4*)v1A, (const float4*)v1B, distG);
  select_kernel<<<dim3(NQ_, T_), 256, 0, stream>>>(distG, sel_n, sel_w, wsumv);
  agg_kernel<<<dim3(64, T_, 2), 1024, 0, stream>>>(
      (const float4*)v2A, (const float4*)v2B, sel_n, sel_w, wsumv, Y);
}

// Round 21
// 241.534 us; speedup vs baseline: 1.1077x; 1.1077x over previous
//
#include <hip/hip_runtime.h>
#include <hip/hip_bf16.h>

#define T_ 4
#define C_ 64
#define H_ 128
#define W_ 128
#define CI_ 16
#define PS_ 7
#define NC_ 729       // 27*27 candidates per query
#define NCP_ 732      // distG row stride: 732 = 4*183 -> every row 16B-aligned
#define S0_ 4
#define KS_ 100
#define NQ_ 1024      // 32*32 queries per frame
#define SCALE_ 10.0f
#define HW_ (H_*W_)
#define RW_ 45        // 4x4-tile region dim (float4); 45%8=5 -> bank rotation
#define LCAP_ 768
#define CB_ 8         // conv channel batch (24 dwordx4 in flight)
#define CH_ 32        // conv input-channel half (2x grid -> 4 waves/SIMD)

typedef float v2f __attribute__((ext_vector_type(2)));
#if __has_builtin(__builtin_elementwise_fma)
#define VFMA(a, b, c) __builtin_elementwise_fma((a), (b), (c))
#else
#define VFMA(a, b, c) ((a) * (b) + (c))
#endif

__device__ __forceinline__ float4 f4add(float4 a, float4 b) {
  return make_float4(a.x + b.x, a.y + b.y, a.z + b.z, a.w + b.w);
}

// ------- FUSED conv 3x3 + conv 1x1, INPUT-CHANNEL-SPLIT (R14-verified) ------
__device__ __forceinline__ float4 colfix(float4 r, bool loB, bool hiB) {
  float4 o;
  o.x = loB ? 0.f : (hiB ? r.y : r.x);
  o.y = loB ? r.x : (hiB ? r.z : r.y);
  o.z = loB ? r.y : (hiB ? r.w : r.z);
  o.w = loB ? r.z : (hiB ? 0.f : r.w);
  return o;
}

__global__ __launch_bounds__(128, 1) void conv_fused_kernel(
    const float* __restrict__ vid, const float* __restrict__ gw,
    const float* __restrict__ gb, const float* __restrict__ tw,
    const float* __restrict__ tb, float4* __restrict__ v1A,
    float4* __restrict__ v1B, float4* __restrict__ v2A,
    float4* __restrict__ v2B) {
  __shared__ float wls[CH_ * 9 * 4];   // 3x3 weights [c_loc][k][co]
  __shared__ float tls[CH_ * 4];       // 1x1 weights [c_loc][co]
  const int tid = threadIdx.x;
  const int g = blockIdx.y;
  const int t = blockIdx.z & 3, half = blockIdx.z >> 2;
  for (int m = tid; m < CH_ * 9 * 4; m += 128) {
    int co = m & 3, ck = m >> 2;       // ck = c_loc*9 + k in [0,288)
    wls[m] = gw[((size_t)(g * 4 + co) * C_) * 9 + half * (CH_ * 9) + ck];
  }
  for (int m = tid; m < CH_ * 4; m += 128) {
    int o = m & 3, c = m >> 2;
    tls[m] = tw[(g * 4 + o) * C_ + half * CH_ + c];
  }
  __syncthreads();
  const int ti0 = (blockIdx.x >> 3) * 16, tj0 = (blockIdx.x & 7) * 16;
  const int u = tid >> 3, v = tid & 7;   // 16 rows x 8 col-pairs
  const int i = ti0 + u, j0 = tj0 + 2 * v;
  const int c0 = j0 - 1;
  const int c0c = min(max(c0, 0), W_ - 4);
  const bool loB = (c0 < 0), hiB = (c0 > W_ - 4);
  const int rm1 = max(i - 1, 0), rp1 = min(i + 1, H_ - 1);
  const float mk0 = (i > 0) ? 1.f : 0.f;
  const float mk2 = (i < H_ - 1) ? 1.f : 0.f;
  const int o0 = rm1 * W_ + c0c, o1 = i * W_ + c0c, o2 = rp1 * W_ + c0c;

  float accA[4], accB[4], acc1A[4], acc1B[4];
#pragma unroll
  for (int co = 0; co < 4; ++co) {     // bias carried by half 0 only
    float bg = half ? 0.f : gb[g * 4 + co];
    float bt = half ? 0.f : tb[g * 4 + co];
    accA[co] = bg; accB[co] = bg;
    acc1A[co] = bt; acc1B[co] = bt;
  }

  const float* vb = vid + ((size_t)t * C_ + half * CH_) * HW_;
#pragma unroll 1
  for (int cb = 0; cb < CH_; cb += CB_) {
    float4 r[CB_][3];
#pragma unroll
    for (int c = 0; c < CB_; ++c) {       // 24 UNCONDITIONAL loads -> in flight
      const float* p = vb + (size_t)(cb + c) * HW_;
      r[c][0] = *(const float4*)(p + o0);
      r[c][1] = *(const float4*)(p + o1);
      r[c][2] = *(const float4*)(p + o2);
    }
#pragma unroll
    for (int c = 0; c < CB_; ++c) {
      float4 f0 = colfix(r[c][0], loB, hiB);
      float4 f1 = colfix(r[c][1], loB, hiB);
      float4 f2 = colfix(r[c][2], loB, hiB);
      f0.x *= mk0; f0.y *= mk0; f0.z *= mk0; f0.w *= mk0;
      f2.x *= mk2; f2.y *= mk2; f2.z *= mk2; f2.w *= mk2;
      const float* wc = &wls[(cb + c) * 36];
      const float* tc = &tls[(cb + c) * 4];
      float e0[4] = {f0.x, f0.y, f0.z, f0.w};
      float e1[4] = {f1.x, f1.y, f1.z, f1.w};
      float e2[4] = {f2.x, f2.y, f2.z, f2.w};
#pragma unroll
      for (int co = 0; co < 4; ++co) {     // fused 1x1: center pixels j0, j0+1
        acc1A[co] = fmaf(tc[co], e1[1], acc1A[co]);
        acc1B[co] = fmaf(tc[co], e1[2], acc1B[co]);
      }
#pragma unroll
      for (int kj = 0; kj < 3; ++kj) {
#pragma unroll
        for (int co = 0; co < 4; ++co) {
          accA[co] = fmaf(wc[(0 * 3 + kj) * 4 + co], e0[kj],     accA[co]);
          accB[co] = fmaf(wc[(0 * 3 + kj) * 4 + co], e0[kj + 1], accB[co]);
          accA[co] = fmaf(wc[(1 * 3 + kj) * 4 + co], e1[kj],     accA[co]);
          accB[co] = fmaf(wc[(1 * 3 + kj) * 4 + co], e1[kj + 1], accB[co]);
          accA[co] = fmaf(wc[(2 * 3 + kj) * 4 + co], e2[kj],     accA[co]);
          accB[co] = fmaf(wc[(2 * 3 + kj) * 4 + co], e2[kj + 1], accB[co]);
        }
      }
    }
  }
  float4* v1o = half ? v1B : v1A;
  float4* v2o = half ? v2B : v2A;
  const size_t o = ((size_t)g * T_ + t) * HW_ + i * W_ + j0;
  v1o[o]     = make_float4(accA[0], accA[1], accA[2], accA[3]);
  v1o[o + 1] = make_float4(accB[0], accB[1], accB[2], accB[3]);
  v2o[o]     = make_float4(acc1A[0], acc1A[1], acc1A[2], acc1A[3]);
  v2o[o + 1] = make_float4(acc1B[0], acc1B[1], acc1B[2], acc1B[3]);
}

// ---------------- dists: query-PAIR per wave, mono launch (R15/R18-proven) --
// 69.5-74us, VGPR 88, no spill. Design space CLOSED (R4-R8, R17, R19):
// >=512-thr blocks don't co-schedule 2/CU; multi-block launch-bounds targets
// force a 64-VGPR budget -> ~90-reg spill; 256-thr split (R19) hit both.
__global__ __launch_bounds__(512, 2) void dist_kernel(
    const float4* __restrict__ v1A, const float4* __restrict__ v1B,
    float* __restrict__ out) {
  __shared__ float4 Rs[2][2048];                 // 2 x 45*45 (padded) = 64 KiB
  const int tid = threadIdx.x;
  const int t = blockIdx.y;
  const int qi0 = (blockIdx.x >> 3) * 16, qj0 = (blockIdx.x & 7) * 16;
  const int w = tid >> 6, lane = tid & 63;
  const int pr = w >> 2, dj = (w & 3) * 4;       // pair-row {0,1}, col-tile
  const int rbase = 8 * pr;
  const int qi_p = qi0 + rbase;                  // q0 pixel row; q1 = qi_p+4
  const int qj = qj0 + dj;
  const int la = lane >> 1, bg = lane & 1;
  const int b_lo = max(13 - qj, 0);
  const int bs = bg ? 13 : b_lo;
  const int a_lo0 = max(13 - qi_p, 0);
  const int a_lo1 = max(9 - qi_p, 0);
  const bool compute_ok = (la < 31);

  // staging: 4 float4 per thread per chunk; source clamped, dest linear
  int soff[4];
#pragma unroll
  for (int k = 0; k < 4; ++k) {
    int p = min(tid + 512 * k, RW_ * RW_ - 1);
    int uu = p / RW_, vv = p - uu * RW_;
    int row = min(max(qi0 - 13 + uu, 0), H_ - 1);
    int col = min(max(qj0 - 13 + vv, 0), W_ - 1);
    soff[k] = row * W_ + col;
  }

  v2f acc0[14], acc1[14];
#pragma unroll
  for (int j = 0; j < 14; ++j) { acc0[j] = (v2f){0.f, 0.f}; acc1[j] = (v2f){0.f, 0.f}; }

  float4 st[4];
  {
    const float4* sA = v1A + ((size_t)0 * T_ + t) * HW_;
    const float4* sB = v1B + ((size_t)0 * T_ + t) * HW_;
#pragma unroll
    for (int k = 0; k < 4; ++k) st[k] = f4add(sA[soff[k]], sB[soff[k]]);
  }
  int cur = 0;
#pragma unroll 1
  for (int ci = 0; ci < 4; ++ci) {
    float4* buf = &Rs[cur][0];
#pragma unroll
    for (int k = 0; k < 4; ++k) buf[tid + 512 * k] = st[k];   // stage chunk ci
    if (ci + 1 < 4) {                                         // prefetch next
      const float4* sA = v1A + ((size_t)(ci + 1) * T_ + t) * HW_;
      const float4* sB = v1B + ((size_t)(ci + 1) * T_ + t) * HW_;
#pragma unroll
      for (int k = 0; k < 4; ++k) st[k] = f4add(sA[soff[k]], sB[soff[k]]);
    }
    __syncthreads();                                          // buf[cur] ready
    if (compute_ok) {
#pragma unroll 1
      for (int r = 0; r < 7; ++r) {
        v2f q0lo[7], q0hi[7], q1lo[7], q1hi[7];
        const float4* q0row = &buf[(rbase + 13 + r) * RW_ + dj + 13];
#pragma unroll
        for (int s = 0; s < 7; ++s) {
          float4 qq = q0row[s];                 // q0 patch row (broadcast)
          q0lo[s] = (v2f){qq.x, qq.y};
          q0hi[s] = (v2f){qq.z, qq.w};
          float4 q2 = q0row[4 * RW_ + s];       // q1 patch row = +4 rows
          q1lo[s] = (v2f){q2.x, q2.y};
          q1hi[s] = (v2f){q2.z, q2.w};
        }
        const float4* crow = &buf[(rbase + la + r) * RW_ + dj + bs];
#pragma unroll
        for (int y = 0; y < 20; ++y) {
          float4 vv4 = crow[y];                 // shared by q0 AND q1
          v2f vlo = (v2f){vv4.x, vv4.y}, vhi = (v2f){vv4.z, vv4.w};
          const int s_lo = (y > 13) ? (y - 13) : 0;
          const int s_hi = (y < 6) ? y : 6;
#pragma unroll
          for (int s = s_lo; s <= s_hi; ++s) {
            int j = y - s;
            acc0[j] = VFMA(q0lo[s], vlo, acc0[j]);
            acc0[j] = VFMA(q0hi[s], vhi, acc0[j]);
            acc1[j] = VFMA(q1lo[s], vlo, acc1[j]);
            acc1[j] = VFMA(q1hi[s], vhi, acc1[j]);
          }
        }
      }
    }
    cur ^= 1;
  }
  if (compute_ok) {
    const int q0q = ((qi_p >> 2) << 5) + (qj >> 2);
    if (la >= a_lo0 && la <= 26) {
      float* o = out + ((size_t)t * NQ_ + q0q) * NCP_ + la * 27 + bs;
#pragma unroll
      for (int j = 0; j < 14; ++j) o[j] = acc0[j].x + acc0[j].y;
    }
    const int a1 = la - 4;
    if (a1 >= a_lo1 && a1 <= 26) {
      float* o = out + ((size_t)t * NQ_ + (q0q + 32)) * NCP_ + a1 * 27 + bs;
#pragma unroll
      for (int j = 0; j < 14; ++j) o[j] = acc1[j].x + acc1[j].y;
    }
  }
}

// ---------------- select: 2-level radix top-100, wave-primitive scans -------
// Interior fast path (77% of queries): clamp remap is identity and the
// 729-row is contiguous + 16B-aligned -> vectorized float4 loads.
__global__ __launch_bounds__(256) void select_kernel(
    const float* __restrict__ distA, int* __restrict__ sel_n,
    float* __restrict__ sel_w, float* __restrict__ wsum_out) {
  __shared__ float dist[NC_];
  __shared__ unsigned int ukey[NC_];
  __shared__ float redf[4];
  __shared__ unsigned int hist[256];
  __shared__ int lk[LCAP_];
  __shared__ unsigned int lkey[LCAP_];
  __shared__ unsigned int scal[6];   // 0=beta 1=run 2=cursor 3=listlen 4=beta2 5=run2

  const int tid = threadIdx.x;
  const int lane = tid & 63, wid = tid >> 6;
  const int q = blockIdx.x, t = blockIdx.y;
  const int qi = (q >> 5) * S0_, qj = (q & 31) * S0_;
  const int a_lo = max(13 - qi, 0), b_lo = max(13 - qj, 0);
  const size_t base = ((size_t)t * NQ_ + q) * NCP_;

  for (int h = tid; h < 256; h += 256) hist[h] = 0;
  if (tid == 0) { scal[2] = 0; scal[3] = 0; }
  float lmax = -INFINITY;
  if (a_lo == 0 && b_lo == 0) {            // interior: vectorized direct load
    if (tid < 182) {
      float4 d4 = *(const float4*)(distA + base + 4 * tid);
      float dv[4] = {d4.x, d4.y, d4.z, d4.w};
#pragma unroll
      for (int e = 0; e < 4; ++e) {
        int k = 4 * tid + e;
        float d = dv[e];
        dist[k] = d;
        unsigned int u = __float_as_uint(d);
        ukey[k] = u ^ (((unsigned int)((int)u >> 31)) | 0x80000000u);
        lmax = fmaxf(lmax, d);
      }
    } else if (tid == 182) {
      float d = distA[base + 728];
      dist[728] = d;
      unsigned int u = __float_as_uint(d);
      ukey[728] = u ^ (((unsigned int)((int)u >> 31)) | 0x80000000u);
      lmax = d;
    }
  } else {                                 // boundary: scalar clamp-gather
    for (int k = tid; k < NC_; k += 256) {
      int aa = k / 27, bb = k - aa * 27;
      int kk = max(aa, a_lo) * 27 + max(bb, b_lo);
      float d = distA[base + kk];
      dist[k] = d;
      unsigned int u = __float_as_uint(d);
      ukey[k] = u ^ (((unsigned int)((int)u >> 31)) | 0x80000000u);
      lmax = fmaxf(lmax, d);
    }
  }
#pragma unroll
  for (int off = 32; off > 0; off >>= 1)
    lmax = fmaxf(lmax, __shfl_down(lmax, off, 64));
  if (lane == 0) redf[wid] = lmax;
  __syncthreads();                                             // B1
  const float dmax = fmaxf(fmaxf(redf[0], redf[1]), fmaxf(redf[2], redf[3]));
  for (int k = tid; k < NC_; k += 256) atomicAdd(&hist[ukey[k] >> 24], 1u);
  __syncthreads();                                             // B2
  if (wid == 0) {
    int s4 = (int)(hist[lane * 4] + hist[lane * 4 + 1] + hist[lane * 4 + 2] + hist[lane * 4 + 3]);
    int s = s4;
#pragma unroll
    for (int off = 1; off < 64; off <<= 1) {
      int o = __shfl_down(s, off, 64);
      if (lane + off < 64) s += o;
    }
    int above = s - s4;
    if (above < KS_ && s >= KS_) {
      int run = above;
#pragma unroll
      for (int bb = 3; bb >= 0; --bb) {
        int h = (int)hist[lane * 4 + bb];
        if (run + h >= KS_) { scal[0] = (unsigned int)(lane * 4 + bb); scal[1] = (unsigned int)run; break; }
        run += h;
      }
    }
  }
  __syncthreads();                                             // B3
  const unsigned int beta = scal[0];
  const int run = (int)scal[1];
  for (int h = tid; h < 256; h += 256) hist[h] = 0;
  __syncthreads();                                             // B4
  for (int k = tid; k < NC_; k += 256)
    if ((ukey[k] >> 24) == beta) atomicAdd(&hist[(ukey[k] >> 16) & 0xFFu], 1u);
  __syncthreads();                                             // B5
  if (wid == 0) {
    int s4 = (int)(hist[lane * 4] + hist[lane * 4 + 1] + hist[lane * 4 + 2] + hist[lane * 4 + 3]);
    int s = s4;
#pragma unroll
    for (int off = 1; off < 64; off <<= 1) {
      int o = __shfl_down(s, off, 64);
      if (lane + off < 64) s += o;
    }
    int above = run + s - s4;
    if (above < KS_ && run + s >= KS_) {
      int r2 = above;
#pragma unroll
      for (int bb = 3; bb >= 0; --bb) {
        int h = (int)hist[lane * 4 + bb];
        if (r2 + h >= KS_) { scal[4] = (unsigned int)(lane * 4 + bb); scal[5] = (unsigned int)r2; break; }
        r2 += h;
      }
    }
  }
  __syncthreads();                                             // B6
  const unsigned int beta2 = scal[4];
  const int run2 = (int)scal[5];
  const size_t outb = ((size_t)t * NQ_ + q) * KS_;
  float lsum = 0.f;
  for (int k = tid; k < NC_; k += 256) {
    unsigned int key = ukey[k];
    unsigned int bin = key >> 24;
    bool sel = false, bdry = false;
    if (bin > beta) sel = true;
    else if (bin == beta) {
      unsigned int b2 = (key >> 16) & 0xFFu;
      if (b2 > beta2) sel = true;
      else if (b2 == beta2) bdry = true;
    }
    if (sel) {
      unsigned int slot = atomicAdd(&scal[2], 1u);
      int aa = k / 27, bb = k - aa * 27;
      int ni = min(max(qi + aa - 13, 0), H_ - 1);
      int nj = min(max(qj + bb - 13, 0), W_ - 1);
      float wv = __expf(SCALE_ * (dist[k] - dmax));
      sel_n[outb + slot] = (ni << 7) | nj;
      sel_w[outb + slot] = wv;
      lsum += wv;
    } else if (bdry) {
      unsigned int pos = atomicAdd(&scal[3], 1u);
      if (pos < LCAP_) { lk[pos] = k; lkey[pos] = key; }
    }
  }
  __syncthreads();                                             // B7
  const int L = min((int)scal[3], LCAP_);
  for (int i = tid; i < L; i += 256) {
    unsigned int key = lkey[i];
    int k = lk[i];
    int cnt = run2;
    for (int m = 0; m < L; ++m)
      cnt += (int)((lkey[m] > key) || (lkey[m] == key && lk[m] < k));
    if (cnt < KS_) {
      unsigned int slot = atomicAdd(&scal[2], 1u);
      int aa = k / 27, bb = k - aa * 27;
      int ni = min(max(qi + aa - 13, 0), H_ - 1);
      int nj = min(max(qj + bb - 13, 0), W_ - 1);
      float wv = __expf(SCALE_ * (dist[k] - dmax));
      sel_n[outb + slot] = (ni << 7) | nj;
      sel_w[outb + slot] = wv;
      lsum += wv;
    }
  }
#pragma unroll
  for (int off = 32; off > 0; off >>= 1) lsum += __shfl_down(lsum, off, 64);
  __syncthreads();                                             // B8
  if (lane == 0) redf[wid] = lsum;
  __syncthreads();                                             // B9
  if (tid == 0) wsum_out[t * NQ_ + q] = (redf[0] + redf[1]) + (redf[2] + redf[3]);
}

// ---------------- fold-count helper (analytic normalization) ----------------
__device__ __forceinline__ int cov_axis(int x) {
  int c = 0;
#pragma unroll
  for (int r = 0; r < 7; ++r) {
    if (x < H_ - 1) {
      int qb = x - r;
      c += (qb >= 0 && (qb & 3) == 0) ? 1 : 0;
    } else {
      c += (r >= 3) ? 1 : 0;
    }
  }
  return c;
}

// ------- weighted aggregation + fold + fused norm, Z-SPLIT (R15-verified) ---
// R16: LDS-pipe-saturated (6400 b128 gathers + conflicts ~ 43us/CU) -> at
// structural floor.
__global__ __launch_bounds__(1024) void agg_kernel(
    const float4* __restrict__ v2A, const float4* __restrict__ v2B,
    const int* __restrict__ sel_n, const float* __restrict__ sel_w,
    const float* __restrict__ wsum, float* __restrict__ Y) {
  __shared__ float4 Rs[RW_ * RW_];
  __shared__ int s_off[16][KS_];
  __shared__ float s_w[16][KS_];
  const int tid = threadIdx.x;
  const int t = blockIdx.y;
  const int cc0 = blockIdx.z * 2;
  const int qi0 = (blockIdx.x >> 3) * 16, qj0 = (blockIdx.x & 7) * 16;
  const int w = tid >> 6, lane = tid & 63;
  const int di = (w >> 2) * 4, dj = (w & 3) * 4;
  const int qi = qi0 + di, qj = qj0 + dj;
  const int q = ((qi >> 2) << 5) + (qj >> 2);
  const size_t base = ((size_t)t * NQ_ + q) * KS_;
  const float inv = 1.0f / wsum[t * NQ_ + q];
  for (int k = lane; k < KS_; k += 64) {
    int n = sel_n[base + k];
    int ni = n >> 7, nj = n & 127;
    s_off[w][k] = (ni - qi0 + 13) * RW_ + (nj - qj0 + 13);
    s_w[w][k] = sel_w[base + k] * inv;
  }
  const int r = lane / 7, s = lane - r * 7;    // valid for lane < 49
  const int myo = r * RW_ + s;
  const int oi = min(qi + r, H_ - 1), oj = min(qj + s, W_ - 1);
  const float invZ = 1.0f / (float)(cov_axis(oi) * cov_axis(oj));
#pragma unroll 1
  for (int ci = 0; ci < 2; ++ci) {
    const int cc = cc0 + ci;
    __syncthreads();
    const float4* sA = v2A + ((size_t)cc * T_ + t) * HW_;
    const float4* sB = v2B + ((size_t)cc * T_ + t) * HW_;
    for (int p = tid; p < RW_ * RW_; p += 1024) {
      int uu = p / RW_, vv = p - uu * RW_;
      int row = min(max(qi0 - 13 + uu, 0), H_ - 1);
      int col = min(max(qj0 - 13 + vv, 0), W_ - 1);
      const int so = row * W_ + col;
      Rs[p] = f4add(sA[so], sB[so]);
    }
    __syncthreads();
    if (lane < 49) {
      float4 acc = make_float4(0.f, 0.f, 0.f, 0.f);
#pragma unroll 4
      for (int k = 0; k < KS_; ++k) {
        float wv = s_w[w][k];
        float4 v = Rs[s_off[w][k] + myo];
        acc.x = fmaf(wv, v.x, acc.x);
        acc.y = fmaf(wv, v.y, acc.y);
        acc.z = fmaf(wv, v.z, acc.z);
        acc.w = fmaf(wv, v.w, acc.w);
      }
      float* yb = Y + (((size_t)t * CI_ + cc * 4) * H_ + oi) * W_ + oj;
      atomicAdd(yb, acc.x * invZ);
      atomicAdd(yb + HW_, acc.y * invZ);
      atomicAdd(yb + 2 * HW_, acc.z * invZ);
      atomicAdd(yb + 3 * HW_, acc.w * invZ);
    }
  }
}

extern "C" void kernel_launch(void* const* d_in, const int* in_sizes, int n_in,
                              void* d_out, int out_size, void* d_ws, size_t ws_size,
                              hipStream_t stream) {
  const float* vid     = (const float*)d_in[0];
  const float* g_w     = (const float*)d_in[1];
  const float* g_b     = (const float*)d_in[2];
  const float* theta_w = (const float*)d_in[3];
  const float* theta_b = (const float*)d_in[4];
  float* Y = (float*)d_out;

  // workspace: v1A | v1B | v2A | v2B | distG(NCP_) | sel_n | sel_w | wsum
  const size_t VSZ = (size_t)4 * T_ * HW_ * 4;                 // 1048576 floats
  float* v1A   = (float*)d_ws;
  float* v1B   = v1A + VSZ;
  float* v2A   = v1B + VSZ;
  float* v2B   = v2A + VSZ;
  float* distG = v2B + VSZ;
  int*   sel_n = (int*)(distG + (size_t)T_ * NQ_ * NCP_);      // 2998272
  float* sel_w = (float*)(sel_n + (size_t)T_ * NQ_ * KS_);     // 409600
  float* wsumv = sel_w + (size_t)T_ * NQ_ * KS_;               // 409600

  hipMemsetAsync(Y, 0, (size_t)out_size * sizeof(float), stream);

  conv_fused_kernel<<<dim3(64, 4, 2 * T_), 128, 0, stream>>>(
      vid, g_w, g_b, theta_w, theta_b,
      (float4*)v1A, (float4*)v1B, (float4*)v2A, (float4*)v2B);
  dist_kernel<<<dim3(64, T_), 512, 0, stream>>>(
      (const float4*)v1A, (const float4*)v1B, distG);
  select_kernel<<<dim3(NQ_, T_), 256, 0, stream>>>(distG, sel_n, sel_w, wsumv);
  agg_kernel<<<dim3(64, T_, 2), 1024, 0, stream>>>(
      (const float4*)v2A, (const float4*)v2B, sel_n, sel_w, wsumv, Y);
}